// Round 11
// baseline (87.668 us; speedup 1.0000x reference)
//
#include <hip/hip_runtime.h>
#include <hip/hip_bf16.h>

typedef __attribute__((ext_vector_type(8))) short bf16x8;
typedef __attribute__((ext_vector_type(4))) short bf16x4;
typedef __attribute__((ext_vector_type(4))) float f32x4;

#define MFMA16(a, b, c) __builtin_amdgcn_mfma_f32_16x16x32_bf16(a, b, c, 0, 0, 0)
#define VMCNT4() asm volatile("s_waitcnt vmcnt(4)" ::: "memory")
#define VMCNT0() asm volatile("s_waitcnt vmcnt(0)" ::: "memory")

__device__ __forceinline__ unsigned short f2bf(float f) {
  unsigned u = __float_as_uint(f);
  u += 0x7fff + ((u >> 16) & 1);          // RNE, matches jnp bf16 cast
  return (unsigned short)(u >> 16);
}
__device__ __forceinline__ float bf2f(unsigned short s) {
  return __uint_as_float(((unsigned)s) << 16);
}
__device__ __forceinline__ void gload16(const unsigned short* g, unsigned short* l) {
  __builtin_amdgcn_global_load_lds((const __attribute__((address_space(1))) void*)g,
                                   (__attribute__((address_space(3))) void*)l, 16, 0, 0);
}
// XCD-chunked bijective remap of the HW linear block id (nwg % 8 == 0)
__device__ __forceinline__ int xcd_swz(int lin, int nwg) {
  int cpx = nwg >> 3;
  return (lin & 7) * cpx + (lin >> 3);
}

// ---------- merged prep: x+struct_embed -> bf16; wqkv,wout f32 -> bf16 ----------
__global__ __launch_bounds__(256) void prep_all(const float* __restrict__ x,
                                                const int* __restrict__ idx,
                                                const float* __restrict__ se,
                                                const float* __restrict__ wqkv,
                                                const float* __restrict__ wout,
                                                unsigned short* __restrict__ xb,
                                                unsigned short* __restrict__ wqkvb,
                                                unsigned short* __restrict__ woutb) {
  int bid = blockIdx.x;
  int tid = threadIdx.x;
  if (bid < 3072) {                       // prep_x: 4096*192 float4
    int i = bid * 256 + tid;
    int row = i / 192, c4 = i % 192;
    int id = idx[row];
    int sid = (id == 1) ? 1 : (id == 2) ? 2 : (id == 3) ? 3 : 0;
    float4 v = ((const float4*)x)[i];
    float4 s = ((const float4*)se)[sid * 192 + c4];
    ushort4 o;
    o.x = f2bf(v.x + s.x); o.y = f2bf(v.y + s.y);
    o.z = f2bf(v.z + s.z); o.w = f2bf(v.w + s.w);
    *(ushort4*)(xb + (size_t)i * 4) = o;
  } else if (bid < 3072 + 1728) {         // wqkv: 442368 float4
    int i = (bid - 3072) * 256 + tid;
    float4 v = ((const float4*)wqkv)[i];
    ushort4 u;
    u.x = f2bf(v.x); u.y = f2bf(v.y); u.z = f2bf(v.z); u.w = f2bf(v.w);
    ((ushort4*)wqkvb)[i] = u;
  } else {                                // wout: 147456 float4
    int i = (bid - 4800) * 256 + tid;
    float4 v = ((const float4*)wout)[i];
    ushort4 u;
    u.x = f2bf(v.x); u.y = f2bf(v.y); u.z = f2bf(v.z); u.w = f2bf(v.w);
    ((ushort4*)woutb)[i] = u;
  }
}

// ---------- GEMM qkv 128x128, 3-ring counted-vmcnt (R6-proven), T1 swizzle ----------
// Ledger: per iter {vmcnt(4) -> s_barrier -> stage(i+2) -> compute(i)}.
// vmcnt BEFORE barrier => after barrier all waves' tile-i loads landed; stage(i+2)
// overwrites buf (i-1)%3 only after barrier proves all waves finished compute(i-1).
__global__ __launch_bounds__(256) void gemm_qkv(const unsigned short* __restrict__ A,
                                                const unsigned short* __restrict__ B,
                                                unsigned short* __restrict__ Cout,
                                                unsigned short* __restrict__ vT,
                                                int N, int K) {
  __shared__ unsigned short As[3][4096];   // [buf][row 128][k 32]
  __shared__ unsigned short Bs[3][4096];
  int tid = threadIdx.x;
  int lane = tid & 63, wid = tid >> 6;
  int l15 = lane & 15, lhi = lane >> 4;
  int wr = wid >> 1, wc = wid & 1;
  // T1: chunk HW-linear id so each XCD works on ~4 tm-rows x all tn (L2-fits A+B)
  int gy = gridDim.y;
  int lin = blockIdx.x + gridDim.x * blockIdx.y;           // HW dispatch order
  int swz = xcd_swz(lin, gridDim.x * gy);
  long tm = (long)(swz / gy) * 128;
  long tn = (long)(swz % gy) * 128;
  f32x4 acc[4][4];
  const f32x4 z4 = {0.f, 0.f, 0.f, 0.f};
  for (int i = 0; i < 4; ++i)
    for (int j = 0; j < 4; ++j) acc[i][j] = z4;

  int wbase = tid & ~63;                  // wave-uniform LDS chunk base
  int row0 = tid >> 2;                    // 0..63
  int kc = (tid & 3) * 8;
  const unsigned short* Ar0 = &A[(tm + row0) * (long)K + kc];
  const unsigned short* Ar1 = &A[(tm + 64 + row0) * (long)K + kc];
  const unsigned short* Br0 = &B[(tn + row0) * (long)K + kc];
  const unsigned short* Br1 = &B[(tn + 64 + row0) * (long)K + kc];

  auto stage = [&](int b, int k0) {
    gload16(Ar0 + k0, &As[b][wbase * 8]);
    gload16(Ar1 + k0, &As[b][2048 + wbase * 8]);
    gload16(Br0 + k0, &Bs[b][wbase * 8]);
    gload16(Br1 + k0, &Bs[b][2048 + wbase * 8]);
  };

  stage(0, 0);
  stage(1, 32);
  int bc = 0, bp = 2;                     // compute buf, prefetch buf (ring of 3)
  for (int k0 = 0; k0 < K; k0 += 32) {
    if (k0 + 32 < K) VMCNT4(); else VMCNT0();   // own tile-k0 loads landed (4 remain)
    __builtin_amdgcn_s_barrier();               // => all waves' tile-k0 loads landed
    if (k0 + 64 < K) stage(bp, k0 + 64);        // buf (bc-1): free after barrier
    bf16x8 af[4], bfr[4];
#pragma unroll
    for (int mi = 0; mi < 4; ++mi)
      af[mi] = *(const bf16x8*)&As[bc][(wr * 64 + mi * 16 + l15) * 32 + lhi * 8];
#pragma unroll
    for (int nj = 0; nj < 4; ++nj)
      bfr[nj] = *(const bf16x8*)&Bs[bc][(wc * 64 + nj * 16 + l15) * 32 + lhi * 8];
#pragma unroll
    for (int mi = 0; mi < 4; ++mi)
#pragma unroll
      for (int nj = 0; nj < 4; ++nj)
        acc[mi][nj] = MFMA16(af[mi], bfr[nj], acc[mi][nj]);
    bc = (bc == 2) ? 0 : bc + 1;
    bp = (bp == 2) ? 0 : bp + 1;
  }

  if (tn >= 1536) {
    // write V transposed: vT[bh][d][t]
    int b = (int)(tm >> 10);
    int hbase = (int)((tn - 1536) >> 6) + wc;
    int tb = (int)(tm & 1023) + wr * 64 + lhi * 4;
#pragma unroll
    for (int nj = 0; nj < 4; ++nj) {
      int dd = nj * 16 + l15;
      size_t vbase = ((size_t)(b * 12 + hbase)) * 65536 + (size_t)dd * 1024;
#pragma unroll
      for (int mi = 0; mi < 4; ++mi) {
        ushort4 o;
        o.x = f2bf(acc[mi][nj][0]); o.y = f2bf(acc[mi][nj][1]);
        o.z = f2bf(acc[mi][nj][2]); o.w = f2bf(acc[mi][nj][3]);
        *(ushort4*)&vT[vbase + tb + mi * 16] = o;
      }
    }
    return;
  }

#pragma unroll
  for (int mi = 0; mi < 4; ++mi) {
    long row = tm + wr * 64 + mi * 16 + lhi * 4;
#pragma unroll
    for (int nj = 0; nj < 4; ++nj) {
      long col = tn + wc * 64 + nj * 16 + l15;
#pragma unroll
      for (int r = 0; r < 4; ++r)
        Cout[(row + r) * (long)N + col] = f2bf(acc[mi][nj][r]);
    }
  }
}

// ---------- GEMM TM=64 TN=64 (grid 768 = 3 blocks/CU): out = attn @ wout^T + bias ----
__global__ __launch_bounds__(256) void gemm_out(const unsigned short* __restrict__ A,
                                                const unsigned short* __restrict__ B,
                                                float* __restrict__ Cout,
                                                const float* __restrict__ bias,
                                                int N, int K) {
  __shared__ unsigned short As[2][64 * 32];        // 4 KB per buf
  __shared__ unsigned short Bs[2][64 * 32];        // 4 KB per buf
  int tid = threadIdx.x;
  int lane = tid & 63, w = tid >> 6;
  int l15 = lane & 15, lhi = lane >> 4;
  int gy = gridDim.y;
  int lin = blockIdx.x + gridDim.x * blockIdx.y;           // HW dispatch order
  int swz = xcd_swz(lin, gridDim.x * gy);
  long tm = (long)(swz / gy) * 64;
  long tn = (long)(swz % gy) * 64;
  f32x4 acc[4];
  const f32x4 z4 = {0.f, 0.f, 0.f, 0.f};
#pragma unroll
  for (int n = 0; n < 4; ++n) acc[n] = z4;

  int wbase8 = (tid & ~63) * 8;           // wave-uniform LDS elem base
  int row0 = tid >> 2;                    // 0..63
  int kc = (tid & 3) * 8;
  const unsigned short* Ar = &A[(tm + row0) * (long)K + kc];
  const unsigned short* Br = &B[(tn + row0) * (long)K + kc];

  auto stage = [&](int b, int k0) {
    gload16(Ar + k0, &As[b][wbase8]);
    gload16(Br + k0, &Bs[b][wbase8]);
  };

  stage(0, 0);
  __syncthreads();
  int buf = 0;
  for (int k0 = 0; k0 < K; k0 += 32) {
    if (k0 + 32 < K) stage(buf ^ 1, k0 + 32);
    bf16x8 af = *(const bf16x8*)&As[buf][(w * 16 + l15) * 32 + lhi * 8];
    bf16x8 bfr[4];
#pragma unroll
    for (int n = 0; n < 4; ++n)
      bfr[n] = *(const bf16x8*)&Bs[buf][(n * 16 + l15) * 32 + lhi * 8];
#pragma unroll
    for (int n = 0; n < 4; ++n)
      acc[n] = MFMA16(af, bfr[n], acc[n]);
    __syncthreads();
    buf ^= 1;
  }

  long row = tm + w * 16 + lhi * 4;
#pragma unroll
  for (int n = 0; n < 4; ++n) {
    long col = tn + n * 16 + l15;
    float bv = bias[col];
#pragma unroll
    for (int r = 0; r < 4; ++r)
      Cout[(row + r) * (long)N + col] = acc[n][r] + bv;
  }
}

// ---------- attention v7: QBLK=64, 2-buf LDS, MFMA denominator, T1 swizzle ----------
__global__ __launch_bounds__(256) void attn_fwd(const unsigned short* __restrict__ qkv,
                                                const unsigned short* __restrict__ vT,
                                                unsigned short* __restrict__ attnb) {
  __shared__ unsigned short Ks[2][4096];   // [key 64][d 64], 16B-chunk XOR-swizzled
  __shared__ unsigned short Vs[2][4096];   // [d 64][t 64], 16B-chunk XOR-swizzled
  int tid = threadIdx.x;
  int lane = tid & 63, w = tid >> 6;
  int l15 = lane & 15, lhi = lane >> 4;
  int sw = l15 & 7;
  // T1: chunk so each XCD owns 6 consecutive heads (1.5 MB K/V fits its L2)
  int lin = blockIdx.x + gridDim.x * blockIdx.y;           // HW dispatch order
  int swz = xcd_swz(lin, 768);
  int qt = swz & 15, bh = swz >> 4;
  int b = bh / 12, h = bh % 12;

  // staging geometry: LDS[row][c] = G[row][c ^ (row&7)], row = tid>>3, c = tid&7
  int r8 = lane >> 3;
  int cK = ((lane & 7) ^ r8) << 3;                  // pre-swizzled source chunk
  int wbase = (tid & ~63) * 8;                      // wave-uniform LDS elem base
  const unsigned short* kg = qkv + (size_t)(b * 1024) * 2304 + 768 + h * 64 + cK;
  const unsigned short* vg = vT + (size_t)bh * 65536 + cK;

  // stage tile 0
#pragma unroll
  for (int p = 0; p < 2; ++p) {
    int row = p * 32 + w * 8 + r8;
    gload16(kg + (size_t)row * 2304, &Ks[0][p * 2048 + wbase]);
    gload16(vg + (size_t)row * 1024, &Vs[0][p * 2048 + wbase]);
  }

  // Q fragment: B-operand for swapped QK^T (col = qrow = l15), k = d = lhi*8+j
  int qrl = w * 16 + l15;                 // row % 64
  bf16x8 qf0 = {0, 0, 0, 0, 0, 0, 0, 0}, qf1 = {0, 0, 0, 0, 0, 0, 0, 0};
  if (qrl % 3 != 0) {
    const unsigned short* qp =
        &qkv[(size_t)(b * 1024 + qt * 64 + qrl) * 2304 + h * 64 + lhi * 8];
    qf0 = *(const bf16x8*)qp;
    qf1 = *(const bf16x8*)(qp + 32);
  }

  const f32x4 z4 = {0.f, 0.f, 0.f, 0.f};
  f32x4 acc[4];
#pragma unroll
  for (int dg = 0; dg < 4; ++dg) acc[dg] = z4;
  f32x4 accd = z4;                        // denominator via MFMA(P, ones)
  const short one_bf = (short)0x3F80;     // bf16 1.0
  const bf16x8 ONES = {one_bf, one_bf, one_bf, one_bf, one_bf, one_bf, one_bf, one_bf};

  __syncthreads();   // drains staged loads + barrier

  int buf = 0;
  for (int t = 0; t < 16; ++t) {
    if (t < 15) {   // issue next tile's loads; they fly under this tile's compute
      size_t k0 = (size_t)(t + 1) * 64;
#pragma unroll
      for (int p = 0; p < 2; ++p) {
        int row = p * 32 + w * 8 + r8;
        gload16(kg + (k0 + row) * 2304, &Ks[buf ^ 1][p * 2048 + wbase]);
        gload16(vg + (size_t)row * 1024 + k0, &Vs[buf ^ 1][p * 2048 + wbase]);
      }
    }
    const unsigned short* ks = Ks[buf];
    const unsigned short* vs = Vs[buf];

    // swapped QK^T: lane holds P[qrow=l15][key g*16+lhi*4+r]
    bf16x8 paf[2];
#pragma unroll
    for (int g = 0; g < 4; ++g) {
      const unsigned short* kr = &ks[(g * 16 + l15) * 64];
      bf16x8 kf0 = *(const bf16x8*)&kr[(lhi ^ sw) << 3];
      bf16x8 kf1 = *(const bf16x8*)&kr[((lhi + 4) ^ sw) << 3];
      f32x4 sg = MFMA16(kf0, qf0, z4);
      sg = MFMA16(kf1, qf1, sg);
#pragma unroll
      for (int r = 0; r < 4; ++r) {
        // p = exp(s/8) = 2^(s*0.125*log2 e); clamps inert (|s|<~2, p in [e^-2,e^2])
        float pv = exp2f(sg[r] * 0.18033688011f);
        paf[g >> 1][(g & 1) * 4 + r] = (short)f2bf(pv);
      }
    }

    // PV + denominator: V-frags as b64 pairs in matching key order
    __builtin_amdgcn_s_setprio(1);
    accd = MFMA16(paf[0], ONES, accd);
    accd = MFMA16(paf[1], ONES, accd);
#pragma unroll
    for (int dg = 0; dg < 4; ++dg) {
      const unsigned short* vr = &vs[(dg * 16 + l15) * 64];
#pragma unroll
      for (int kh = 0; kh < 2; ++kh) {
        int o0 = kh * 32 + lhi * 4;
        int o1 = o0 + 16;
        bf16x4 v0 = *(const bf16x4*)&vr[(((o0 >> 3) ^ sw) << 3) + (o0 & 7)];
        bf16x4 v1 = *(const bf16x4*)&vr[(((o1 >> 3) ^ sw) << 3) + (o1 & 7)];
        bf16x8 vf = __builtin_shufflevector(v0, v1, 0, 1, 2, 3, 4, 5, 6, 7);
        acc[dg] = MFMA16(paf[kh], vf, acc[dg]);
      }
    }
    __builtin_amdgcn_s_setprio(0);
    __syncthreads();   // drains next-tile staging + protects buf swap
    buf ^= 1;
  }

  // denominator for qrow=lhi*4+r sits in accd[r] (replicated over l15) — no shuffles
#pragma unroll
  for (int r = 0; r < 4; ++r) {
    float inv = 1.f / (accd[r] + 1e-10f);
    int orow = qt * 64 + w * 16 + lhi * 4 + r;
    size_t obase = (size_t)(b * 1024 + orow) * 768 + h * 64;
#pragma unroll
    for (int dg = 0; dg < 4; ++dg)
      attnb[obase + dg * 16 + l15] = f2bf(acc[dg][r] * inv);
  }
}

extern "C" void kernel_launch(void* const* d_in, const int* in_sizes, int n_in,
                              void* d_out, int out_size, void* d_ws, size_t ws_size,
                              hipStream_t stream) {
  (void)in_sizes; (void)n_in; (void)out_size; (void)ws_size;
  const float* x    = (const float*)d_in[0];
  const int*   idx  = (const int*)d_in[1];
  const float* se   = (const float*)d_in[2];
  const float* wqkv = (const float*)d_in[3];
  const float* wout = (const float*)d_in[4];
  const float* bout = (const float*)d_in[5];
  float* out = (float*)d_out;

  char* ws = (char*)d_ws;
  unsigned short* xb    = (unsigned short*)(ws);             //  6,291,456 B
  unsigned short* wqkvb = (unsigned short*)(ws + 6291456);   //  3,538,944 B
  unsigned short* woutb = (unsigned short*)(ws + 9830400);   //  1,179,648 B
  unsigned short* qkvb  = (unsigned short*)(ws + 11010048);  // 18,874,368 B (Q/K used)
  unsigned short* vT    = (unsigned short*)(ws + 29884416);  //  6,291,456 B
  unsigned short* attnb = (unsigned short*)(ws + 36175872);  //  6,291,456 B

  prep_all<<<5376, 256, 0, stream>>>(x, idx, se, wqkv, wout, xb, wqkvb, woutb);
  gemm_qkv<<<dim3(32, 18), 256, 0, stream>>>(xb, wqkvb, qkvb, vT, 2304, 768);
  attn_fwd<<<dim3(16, 48), 256, 0, stream>>>(qkvb, vT, attnb);
  gemm_out<<<dim3(64, 12), 256, 0, stream>>>(attnb, woutb, out, bout, 768, 768);
}

// Round 12
// 86.314 us; speedup vs baseline: 1.0157x; 1.0157x over previous
//
#include <hip/hip_runtime.h>
#include <hip/hip_bf16.h>

typedef __attribute__((ext_vector_type(8))) short bf16x8;
typedef __attribute__((ext_vector_type(4))) short bf16x4;
typedef __attribute__((ext_vector_type(4))) float f32x4;

#define MFMA16(a, b, c) __builtin_amdgcn_mfma_f32_16x16x32_bf16(a, b, c, 0, 0, 0)
#define VMCNT4() asm volatile("s_waitcnt vmcnt(4)" ::: "memory")
#define VMCNT0() asm volatile("s_waitcnt vmcnt(0)" ::: "memory")

__device__ __forceinline__ unsigned short f2bf(float f) {
  unsigned u = __float_as_uint(f);
  u += 0x7fff + ((u >> 16) & 1);          // RNE, matches jnp bf16 cast
  return (unsigned short)(u >> 16);
}
__device__ __forceinline__ float bf2f(unsigned short s) {
  return __uint_as_float(((unsigned)s) << 16);
}
__device__ __forceinline__ void gload16(const unsigned short* g, unsigned short* l) {
  __builtin_amdgcn_global_load_lds((const __attribute__((address_space(1))) void*)g,
                                   (__attribute__((address_space(3))) void*)l, 16, 0, 0);
}
// XCD-chunked bijective remap of the HW linear block id (nwg % 8 == 0)
__device__ __forceinline__ int xcd_swz(int lin, int nwg) {
  int cpx = nwg >> 3;
  return (lin & 7) * cpx + (lin >> 3);
}

// ---------- merged prep: x+struct_embed -> bf16; wqkv,wout f32 -> bf16 ----------
__global__ __launch_bounds__(256) void prep_all(const float* __restrict__ x,
                                                const int* __restrict__ idx,
                                                const float* __restrict__ se,
                                                const float* __restrict__ wqkv,
                                                const float* __restrict__ wout,
                                                unsigned short* __restrict__ xb,
                                                unsigned short* __restrict__ wqkvb,
                                                unsigned short* __restrict__ woutb) {
  int bid = blockIdx.x;
  int tid = threadIdx.x;
  if (bid < 3072) {                       // prep_x: 4096*192 float4
    int i = bid * 256 + tid;
    int row = i / 192, c4 = i % 192;
    int id = idx[row];
    int sid = (id == 1) ? 1 : (id == 2) ? 2 : (id == 3) ? 3 : 0;
    float4 v = ((const float4*)x)[i];
    float4 s = ((const float4*)se)[sid * 192 + c4];
    ushort4 o;
    o.x = f2bf(v.x + s.x); o.y = f2bf(v.y + s.y);
    o.z = f2bf(v.z + s.z); o.w = f2bf(v.w + s.w);
    *(ushort4*)(xb + (size_t)i * 4) = o;
  } else if (bid < 3072 + 1728) {         // wqkv: 442368 float4
    int i = (bid - 3072) * 256 + tid;
    float4 v = ((const float4*)wqkv)[i];
    ushort4 u;
    u.x = f2bf(v.x); u.y = f2bf(v.y); u.z = f2bf(v.z); u.w = f2bf(v.w);
    ((ushort4*)wqkvb)[i] = u;
  } else {                                // wout: 147456 float4
    int i = (bid - 4800) * 256 + tid;
    float4 v = ((const float4*)wout)[i];
    ushort4 u;
    u.x = f2bf(v.x); u.y = f2bf(v.y); u.z = f2bf(v.z); u.w = f2bf(v.w);
    ((ushort4*)woutb)[i] = u;
  }
}

// ---------- GEMM 128x128 2-buf (R10-proven): qkv -> bf16 Q/K + transposed V ----------
__global__ __launch_bounds__(256) void gemm_qkv(const unsigned short* __restrict__ A,
                                                const unsigned short* __restrict__ B,
                                                unsigned short* __restrict__ Cout,
                                                unsigned short* __restrict__ vT,
                                                int N, int K) {
  __shared__ unsigned short As[2][4096];   // [buf][row 128][k 32]
  __shared__ unsigned short Bs[2][4096];
  int tid = threadIdx.x;
  int lane = tid & 63, wid = tid >> 6;
  int l15 = lane & 15, lhi = lane >> 4;
  int wr = wid >> 1, wc = wid & 1;
  // T1: chunk HW-linear id so each XCD works on ~4 tm-rows x all tn (L2-fits A+B)
  int gy = gridDim.y;
  int lin = blockIdx.x + gridDim.x * blockIdx.y;           // HW dispatch order
  int swz = xcd_swz(lin, gridDim.x * gy);
  long tm = (long)(swz / gy) * 128;
  long tn = (long)(swz % gy) * 128;
  f32x4 acc[4][4];
  const f32x4 z4 = {0.f, 0.f, 0.f, 0.f};
  for (int i = 0; i < 4; ++i)
    for (int j = 0; j < 4; ++j) acc[i][j] = z4;

  int wbase = tid & ~63;                  // wave-uniform LDS chunk base
  int row0 = tid >> 2;                    // 0..63
  int kc = (tid & 3) * 8;
  const unsigned short* Ar0 = &A[(tm + row0) * (long)K + kc];
  const unsigned short* Ar1 = &A[(tm + 64 + row0) * (long)K + kc];
  const unsigned short* Br0 = &B[(tn + row0) * (long)K + kc];
  const unsigned short* Br1 = &B[(tn + 64 + row0) * (long)K + kc];

  auto stage = [&](int b, int k0) {
    gload16(Ar0 + k0, &As[b][wbase * 8]);
    gload16(Ar1 + k0, &As[b][2048 + wbase * 8]);
    gload16(Br0 + k0, &Bs[b][wbase * 8]);
    gload16(Br1 + k0, &Bs[b][2048 + wbase * 8]);
  };

  stage(0, 0);
  __syncthreads();                        // tile 0 resident
  int buf = 0;
  for (int k0 = 0; k0 < K; k0 += 32) {
    if (k0 + 32 < K) stage(buf ^ 1, k0 + 32);   // flies under this tile's MFMA
    bf16x8 af[4], bfr[4];
#pragma unroll
    for (int mi = 0; mi < 4; ++mi)
      af[mi] = *(const bf16x8*)&As[buf][(wr * 64 + mi * 16 + l15) * 32 + lhi * 8];
#pragma unroll
    for (int nj = 0; nj < 4; ++nj)
      bfr[nj] = *(const bf16x8*)&Bs[buf][(wc * 64 + nj * 16 + l15) * 32 + lhi * 8];
#pragma unroll
    for (int mi = 0; mi < 4; ++mi)
#pragma unroll
      for (int nj = 0; nj < 4; ++nj)
        acc[mi][nj] = MFMA16(af[mi], bfr[nj], acc[mi][nj]);
    __syncthreads();                      // drains prefetch + protects frag reads
    buf ^= 1;
  }

  if (tn >= 1536) {
    // write V transposed: vT[bh][d][t]
    int b = (int)(tm >> 10);
    int hbase = (int)((tn - 1536) >> 6) + wc;
    int tb = (int)(tm & 1023) + wr * 64 + lhi * 4;
#pragma unroll
    for (int nj = 0; nj < 4; ++nj) {
      int dd = nj * 16 + l15;
      size_t vbase = ((size_t)(b * 12 + hbase)) * 65536 + (size_t)dd * 1024;
#pragma unroll
      for (int mi = 0; mi < 4; ++mi) {
        ushort4 o;
        o.x = f2bf(acc[mi][nj][0]); o.y = f2bf(acc[mi][nj][1]);
        o.z = f2bf(acc[mi][nj][2]); o.w = f2bf(acc[mi][nj][3]);
        *(ushort4*)&vT[vbase + tb + mi * 16] = o;
      }
    }
    return;
  }

#pragma unroll
  for (int mi = 0; mi < 4; ++mi) {
    long row = tm + wr * 64 + mi * 16 + lhi * 4;
#pragma unroll
    for (int nj = 0; nj < 4; ++nj) {
      long col = tn + wc * 64 + nj * 16 + l15;
#pragma unroll
      for (int r = 0; r < 4; ++r)
        Cout[(row + r) * (long)N + col] = f2bf(acc[mi][nj][r]);
    }
  }
}

// ---------- GEMM TM=64 TN=64 (grid 768 = 3 blocks/CU): out = attn @ wout^T + bias ----
__global__ __launch_bounds__(256) void gemm_out(const unsigned short* __restrict__ A,
                                                const unsigned short* __restrict__ B,
                                                float* __restrict__ Cout,
                                                const float* __restrict__ bias,
                                                int N, int K) {
  __shared__ unsigned short As[2][64 * 32];        // 4 KB per buf
  __shared__ unsigned short Bs[2][64 * 32];        // 4 KB per buf
  int tid = threadIdx.x;
  int lane = tid & 63, w = tid >> 6;
  int l15 = lane & 15, lhi = lane >> 4;
  int gy = gridDim.y;
  int lin = blockIdx.x + gridDim.x * blockIdx.y;           // HW dispatch order
  int swz = xcd_swz(lin, gridDim.x * gy);
  long tm = (long)(swz / gy) * 64;
  long tn = (long)(swz % gy) * 64;
  f32x4 acc[4];
  const f32x4 z4 = {0.f, 0.f, 0.f, 0.f};
#pragma unroll
  for (int n = 0; n < 4; ++n) acc[n] = z4;

  int wbase8 = (tid & ~63) * 8;           // wave-uniform LDS elem base
  int row0 = tid >> 2;                    // 0..63
  int kc = (tid & 3) * 8;
  const unsigned short* Ar = &A[(tm + row0) * (long)K + kc];
  const unsigned short* Br = &B[(tn + row0) * (long)K + kc];

  auto stage = [&](int b, int k0) {
    gload16(Ar + k0, &As[b][wbase8]);
    gload16(Br + k0, &Bs[b][wbase8]);
  };

  stage(0, 0);
  __syncthreads();
  int buf = 0;
  for (int k0 = 0; k0 < K; k0 += 32) {
    if (k0 + 32 < K) stage(buf ^ 1, k0 + 32);
    bf16x8 af = *(const bf16x8*)&As[buf][(w * 16 + l15) * 32 + lhi * 8];
    bf16x8 bfr[4];
#pragma unroll
    for (int n = 0; n < 4; ++n)
      bfr[n] = *(const bf16x8*)&Bs[buf][(n * 16 + l15) * 32 + lhi * 8];
#pragma unroll
    for (int n = 0; n < 4; ++n)
      acc[n] = MFMA16(af, bfr[n], acc[n]);
    __syncthreads();
    buf ^= 1;
  }

  long row = tm + w * 16 + lhi * 4;
#pragma unroll
  for (int n = 0; n < 4; ++n) {
    long col = tn + n * 16 + l15;
    float bv = bias[col];
#pragma unroll
    for (int r = 0; r < 4; ++r)
      Cout[(row + r) * (long)N + col] = acc[n][r] + bv;
  }
}

// ---------- attention v8: QBLK=64 (grid 768 unchanged), 3-ring counted-vmcnt --------
// Ledger per iter: {vmcnt(4) -> s_barrier -> stage(t+2) -> compute(t)}. Q-frag loads
// issued BEFORE stage(0/1) so at t=0 the oldest 6 outstanding = {qf:2, tile0:4} and
// vmcnt(4) proves both landed. Steady state: 8 outstanding (t+1, t+2), wait to 4.
__global__ __launch_bounds__(256) void attn_fwd(const unsigned short* __restrict__ qkv,
                                                const unsigned short* __restrict__ vT,
                                                unsigned short* __restrict__ attnb) {
  __shared__ unsigned short Ks[3][4096];   // [key 64][d 64], 16B-chunk XOR-swizzled
  __shared__ unsigned short Vs[3][4096];   // [d 64][t 64], 16B-chunk XOR-swizzled
  int tid = threadIdx.x;
  int lane = tid & 63, w = tid >> 6;
  int l15 = lane & 15, lhi = lane >> 4;
  int sw = l15 & 7;
  // T1: chunk so each XCD owns 6 consecutive heads (1.5 MB K/V fits its L2)
  int lin = blockIdx.x + gridDim.x * blockIdx.y;           // HW dispatch order
  int swz = xcd_swz(lin, 768);
  int qt = swz & 15, bh = swz >> 4;
  int b = bh / 12, h = bh % 12;

  // Q fragment FIRST (oldest in vmcnt ledger): B-operand for swapped QK^T
  int qrl = w * 16 + l15;                 // row % 64
  bf16x8 qf0 = {0, 0, 0, 0, 0, 0, 0, 0}, qf1 = {0, 0, 0, 0, 0, 0, 0, 0};
  if (qrl % 3 != 0) {
    const unsigned short* qp =
        &qkv[(size_t)(b * 1024 + qt * 64 + qrl) * 2304 + h * 64 + lhi * 8];
    qf0 = *(const bf16x8*)qp;
    qf1 = *(const bf16x8*)(qp + 32);
  }

  // staging geometry: LDS[row][c] = G[row][c ^ (row&7)], row = tid>>3, c = tid&7
  int r8 = lane >> 3;
  int cK = ((lane & 7) ^ r8) << 3;                  // pre-swizzled source chunk
  int wbase = (tid & ~63) * 8;                      // wave-uniform LDS elem base
  const unsigned short* kg = qkv + (size_t)(b * 1024) * 2304 + 768 + h * 64 + cK;
  const unsigned short* vg = vT + (size_t)bh * 65536 + cK;

  auto stage = [&](int bufi, int t) {
    size_t k0 = (size_t)t * 64;
#pragma unroll
    for (int p = 0; p < 2; ++p) {
      int row = p * 32 + w * 8 + r8;
      gload16(kg + (k0 + row) * 2304, &Ks[bufi][p * 2048 + wbase]);
      gload16(vg + (size_t)row * 1024 + k0, &Vs[bufi][p * 2048 + wbase]);
    }
  };

  stage(0, 0);
  stage(1, 1);

  const f32x4 z4 = {0.f, 0.f, 0.f, 0.f};
  f32x4 acc[4];
#pragma unroll
  for (int dg = 0; dg < 4; ++dg) acc[dg] = z4;
  f32x4 accd = z4;                        // denominator via MFMA(P, ones)
  const short one_bf = (short)0x3F80;     // bf16 1.0
  const bf16x8 ONES = {one_bf, one_bf, one_bf, one_bf, one_bf, one_bf, one_bf, one_bf};

  int bc = 0, bp = 2;                     // compute buf, prefetch buf (ring of 3)
  for (int t = 0; t < 16; ++t) {
    if (t < 15) VMCNT4(); else VMCNT0();  // own tile-t (and qf at t=0) landed
    __builtin_amdgcn_s_barrier();         // all waves' tile-t loads landed
    if (t + 2 < 16) stage(bp, t + 2);     // buf (bc-1): free after barrier
    const unsigned short* ks = Ks[bc];
    const unsigned short* vs = Vs[bc];

    // swapped QK^T: lane holds P[qrow=l15][key g*16+lhi*4+r]
    bf16x8 paf[2];
#pragma unroll
    for (int g = 0; g < 4; ++g) {
      const unsigned short* kr = &ks[(g * 16 + l15) * 64];
      bf16x8 kf0 = *(const bf16x8*)&kr[(lhi ^ sw) << 3];
      bf16x8 kf1 = *(const bf16x8*)&kr[((lhi + 4) ^ sw) << 3];
      f32x4 sg = MFMA16(kf0, qf0, z4);
      sg = MFMA16(kf1, qf1, sg);
#pragma unroll
      for (int r = 0; r < 4; ++r) {
        // p = exp(s/8) = 2^(s*0.125*log2 e); clamps inert (|s|<~2, p in [e^-2,e^2])
        float pv = exp2f(sg[r] * 0.18033688011f);
        paf[g >> 1][(g & 1) * 4 + r] = (short)f2bf(pv);
      }
    }

    // PV + denominator: V-frags as b64 pairs in matching key order
    __builtin_amdgcn_s_setprio(1);
    accd = MFMA16(paf[0], ONES, accd);
    accd = MFMA16(paf[1], ONES, accd);
#pragma unroll
    for (int dg = 0; dg < 4; ++dg) {
      const unsigned short* vr = &vs[(dg * 16 + l15) * 64];
#pragma unroll
      for (int kh = 0; kh < 2; ++kh) {
        int o0 = kh * 32 + lhi * 4;
        int o1 = o0 + 16;
        bf16x4 v0 = *(const bf16x4*)&vr[(((o0 >> 3) ^ sw) << 3) + (o0 & 7)];
        bf16x4 v1 = *(const bf16x4*)&vr[(((o1 >> 3) ^ sw) << 3) + (o1 & 7)];
        bf16x8 vf = __builtin_shufflevector(v0, v1, 0, 1, 2, 3, 4, 5, 6, 7);
        acc[dg] = MFMA16(paf[kh], vf, acc[dg]);
      }
    }
    __builtin_amdgcn_s_setprio(0);
    bc = (bc == 2) ? 0 : bc + 1;
    bp = (bp == 2) ? 0 : bp + 1;
  }

  // denominator for qrow=lhi*4+r sits in accd[r] (replicated over l15) — no shuffles
#pragma unroll
  for (int r = 0; r < 4; ++r) {
    float inv = 1.f / (accd[r] + 1e-10f);
    int orow = qt * 64 + w * 16 + lhi * 4 + r;
    size_t obase = (size_t)(b * 1024 + orow) * 768 + h * 64;
#pragma unroll
    for (int dg = 0; dg < 4; ++dg)
      attnb[obase + dg * 16 + l15] = f2bf(acc[dg][r] * inv);
  }
}

extern "C" void kernel_launch(void* const* d_in, const int* in_sizes, int n_in,
                              void* d_out, int out_size, void* d_ws, size_t ws_size,
                              hipStream_t stream) {
  (void)in_sizes; (void)n_in; (void)out_size; (void)ws_size;
  const float* x    = (const float*)d_in[0];
  const int*   idx  = (const int*)d_in[1];
  const float* se   = (const float*)d_in[2];
  const float* wqkv = (const float*)d_in[3];
  const float* wout = (const float*)d_in[4];
  const float* bout = (const float*)d_in[5];
  float* out = (float*)d_out;

  char* ws = (char*)d_ws;
  unsigned short* xb    = (unsigned short*)(ws);             //  6,291,456 B
  unsigned short* wqkvb = (unsigned short*)(ws + 6291456);   //  3,538,944 B
  unsigned short* woutb = (unsigned short*)(ws + 9830400);   //  1,179,648 B
  unsigned short* qkvb  = (unsigned short*)(ws + 11010048);  // 18,874,368 B (Q/K used)
  unsigned short* vT    = (unsigned short*)(ws + 29884416);  //  6,291,456 B
  unsigned short* attnb = (unsigned short*)(ws + 36175872);  //  6,291,456 B

  prep_all<<<5376, 256, 0, stream>>>(x, idx, se, wqkv, wout, xb, wqkvb, woutb);
  gemm_qkv<<<dim3(32, 18), 256, 0, stream>>>(xb, wqkvb, qkvb, vT, 2304, 768);
  attn_fwd<<<dim3(16, 48), 256, 0, stream>>>(qkvb, vT, attnb);
  gemm_out<<<dim3(64, 12), 256, 0, stream>>>(attnb, woutb, out, bout, 768, 768);
}

// Round 13
// 82.545 us; speedup vs baseline: 1.0621x; 1.0457x over previous
//
#include <hip/hip_runtime.h>
#include <hip/hip_bf16.h>

typedef __attribute__((ext_vector_type(8))) short bf16x8;
typedef __attribute__((ext_vector_type(4))) float f32x4;

#define MFMA16(a, b, c) __builtin_amdgcn_mfma_f32_16x16x32_bf16(a, b, c, 0, 0, 0)
#define VMCNT4() asm volatile("s_waitcnt vmcnt(4)" ::: "memory")
#define VMCNT0() asm volatile("s_waitcnt vmcnt(0)" ::: "memory")

__device__ __forceinline__ unsigned short f2bf(float f) {
  unsigned u = __float_as_uint(f);
  u += 0x7fff + ((u >> 16) & 1);          // RNE, matches jnp bf16 cast
  return (unsigned short)(u >> 16);
}
__device__ __forceinline__ float bf2f(unsigned short s) {
  return __uint_as_float(((unsigned)s) << 16);
}
__device__ __forceinline__ void gload16(const unsigned short* g, unsigned short* l) {
  __builtin_amdgcn_global_load_lds((const __attribute__((address_space(1))) void*)g,
                                   (__attribute__((address_space(3))) void*)l, 16, 0, 0);
}
// XCD-chunked bijective remap of the HW linear block id (nwg % 8 == 0)
__device__ __forceinline__ int xcd_swz(int lin, int nwg) {
  int cpx = nwg >> 3;
  return (lin & 7) * cpx + (lin >> 3);
}

// ---------- merged prep: x+struct_embed -> bf16; wqkv,wout f32 -> bf16 ----------
__global__ __launch_bounds__(256) void prep_all(const float* __restrict__ x,
                                                const int* __restrict__ idx,
                                                const float* __restrict__ se,
                                                const float* __restrict__ wqkv,
                                                const float* __restrict__ wout,
                                                unsigned short* __restrict__ xb,
                                                unsigned short* __restrict__ wqkvb,
                                                unsigned short* __restrict__ woutb) {
  int bid = blockIdx.x;
  int tid = threadIdx.x;
  if (bid < 3072) {                       // prep_x: 4096*192 float4
    int i = bid * 256 + tid;
    int row = i / 192, c4 = i % 192;
    int id = idx[row];
    int sid = (id == 1) ? 1 : (id == 2) ? 2 : (id == 3) ? 3 : 0;
    float4 v = ((const float4*)x)[i];
    float4 s = ((const float4*)se)[sid * 192 + c4];
    ushort4 o;
    o.x = f2bf(v.x + s.x); o.y = f2bf(v.y + s.y);
    o.z = f2bf(v.z + s.z); o.w = f2bf(v.w + s.w);
    *(ushort4*)(xb + (size_t)i * 4) = o;
  } else if (bid < 3072 + 1728) {         // wqkv: 442368 float4
    int i = (bid - 3072) * 256 + tid;
    float4 v = ((const float4*)wqkv)[i];
    ushort4 u;
    u.x = f2bf(v.x); u.y = f2bf(v.y); u.z = f2bf(v.z); u.w = f2bf(v.w);
    ((ushort4*)wqkvb)[i] = u;
  } else {                                // wout: 147456 float4
    int i = (bid - 4800) * 256 + tid;
    float4 v = ((const float4*)wout)[i];
    ushort4 u;
    u.x = f2bf(v.x); u.y = f2bf(v.y); u.z = f2bf(v.z); u.w = f2bf(v.w);
    ((ushort4*)woutb)[i] = u;
  }
}

// ---------- GEMM 128x128 2-buf (R10-proven): qkv -> bf16 Q/K + permuted-key vT ------
// vT key permutation (within each 64-key group): t = 32kh+16h+4q+rr stored at
// 32kh+8q+4h+rr, so attention's PV B-fragment (8 keys/lane) is one contiguous
// 16B chunk in LDS. Consumed by attn_fwd with chunk index (4kh+lhi)^sw.
__global__ __launch_bounds__(256) void gemm_qkv(const unsigned short* __restrict__ A,
                                                const unsigned short* __restrict__ B,
                                                unsigned short* __restrict__ Cout,
                                                unsigned short* __restrict__ vT,
                                                int N, int K) {
  __shared__ unsigned short As[2][4096];   // [buf][row 128][k 32]
  __shared__ unsigned short Bs[2][4096];
  int tid = threadIdx.x;
  int lane = tid & 63, wid = tid >> 6;
  int l15 = lane & 15, lhi = lane >> 4;
  int wr = wid >> 1, wc = wid & 1;
  // T1: chunk HW-linear id so each XCD works on ~4 tm-rows x all tn (L2-fits A+B)
  int gy = gridDim.y;
  int lin = blockIdx.x + gridDim.x * blockIdx.y;           // HW dispatch order
  int swz = xcd_swz(lin, gridDim.x * gy);
  long tm = (long)(swz / gy) * 128;
  long tn = (long)(swz % gy) * 128;
  f32x4 acc[4][4];
  const f32x4 z4 = {0.f, 0.f, 0.f, 0.f};
  for (int i = 0; i < 4; ++i)
    for (int j = 0; j < 4; ++j) acc[i][j] = z4;

  int wbase = tid & ~63;                  // wave-uniform LDS chunk base
  int row0 = tid >> 2;                    // 0..63
  int kc = (tid & 3) * 8;
  const unsigned short* Ar0 = &A[(tm + row0) * (long)K + kc];
  const unsigned short* Ar1 = &A[(tm + 64 + row0) * (long)K + kc];
  const unsigned short* Br0 = &B[(tn + row0) * (long)K + kc];
  const unsigned short* Br1 = &B[(tn + 64 + row0) * (long)K + kc];

  auto stage = [&](int b, int k0) {
    gload16(Ar0 + k0, &As[b][wbase * 8]);
    gload16(Ar1 + k0, &As[b][2048 + wbase * 8]);
    gload16(Br0 + k0, &Bs[b][wbase * 8]);
    gload16(Br1 + k0, &Bs[b][2048 + wbase * 8]);
  };

  stage(0, 0);
  __syncthreads();                        // tile 0 resident
  int buf = 0;
  for (int k0 = 0; k0 < K; k0 += 32) {
    if (k0 + 32 < K) stage(buf ^ 1, k0 + 32);   // flies under this tile's MFMA
    bf16x8 af[4], bfr[4];
#pragma unroll
    for (int mi = 0; mi < 4; ++mi)
      af[mi] = *(const bf16x8*)&As[buf][(wr * 64 + mi * 16 + l15) * 32 + lhi * 8];
#pragma unroll
    for (int nj = 0; nj < 4; ++nj)
      bfr[nj] = *(const bf16x8*)&Bs[buf][(wc * 64 + nj * 16 + l15) * 32 + lhi * 8];
#pragma unroll
    for (int mi = 0; mi < 4; ++mi)
#pragma unroll
      for (int nj = 0; nj < 4; ++nj)
        acc[mi][nj] = MFMA16(af[mi], bfr[nj], acc[mi][nj]);
    __syncthreads();                      // drains prefetch + protects frag reads
    buf ^= 1;
  }

  if (tn >= 1536) {
    // write V transposed + key-permuted: keys t0..t0+3 (t0 = tmw + lhi*4 + mi*16)
    // land at within-64 offset (mi>>1)*32 + lhi*8 + (mi&1)*4
    int b = (int)(tm >> 10);
    int hbase = (int)((tn - 1536) >> 6) + wc;
    int tmw = (int)(tm & 1023) + wr * 64;        // 64-aligned key-group base
#pragma unroll
    for (int nj = 0; nj < 4; ++nj) {
      int dd = nj * 16 + l15;
      size_t vbase = ((size_t)(b * 12 + hbase)) * 65536 + (size_t)dd * 1024;
#pragma unroll
      for (int mi = 0; mi < 4; ++mi) {
        ushort4 o;
        o.x = f2bf(acc[mi][nj][0]); o.y = f2bf(acc[mi][nj][1]);
        o.z = f2bf(acc[mi][nj][2]); o.w = f2bf(acc[mi][nj][3]);
        *(ushort4*)&vT[vbase + tmw + (mi >> 1) * 32 + lhi * 8 + (mi & 1) * 4] = o;
      }
    }
    return;
  }

#pragma unroll
  for (int mi = 0; mi < 4; ++mi) {
    long row = tm + wr * 64 + mi * 16 + lhi * 4;
#pragma unroll
    for (int nj = 0; nj < 4; ++nj) {
      long col = tn + wc * 64 + nj * 16 + l15;
#pragma unroll
      for (int r = 0; r < 4; ++r)
        Cout[(row + r) * (long)N + col] = f2bf(acc[mi][nj][r]);
    }
  }
}

// ---------- GEMM TM=64 TN=64 (grid 768 = 3 blocks/CU): out = attn @ wout^T + bias ----
__global__ __launch_bounds__(256) void gemm_out(const unsigned short* __restrict__ A,
                                                const unsigned short* __restrict__ B,
                                                float* __restrict__ Cout,
                                                const float* __restrict__ bias,
                                                int N, int K) {
  __shared__ unsigned short As[2][64 * 32];        // 4 KB per buf
  __shared__ unsigned short Bs[2][64 * 32];        // 4 KB per buf
  int tid = threadIdx.x;
  int lane = tid & 63, w = tid >> 6;
  int l15 = lane & 15, lhi = lane >> 4;
  int gy = gridDim.y;
  int lin = blockIdx.x + gridDim.x * blockIdx.y;           // HW dispatch order
  int swz = xcd_swz(lin, gridDim.x * gy);
  long tm = (long)(swz / gy) * 64;
  long tn = (long)(swz % gy) * 64;
  f32x4 acc[4];
  const f32x4 z4 = {0.f, 0.f, 0.f, 0.f};
#pragma unroll
  for (int n = 0; n < 4; ++n) acc[n] = z4;

  int wbase8 = (tid & ~63) * 8;           // wave-uniform LDS elem base
  int row0 = tid >> 2;                    // 0..63
  int kc = (tid & 3) * 8;
  const unsigned short* Ar = &A[(tm + row0) * (long)K + kc];
  const unsigned short* Br = &B[(tn + row0) * (long)K + kc];

  auto stage = [&](int b, int k0) {
    gload16(Ar + k0, &As[b][wbase8]);
    gload16(Br + k0, &Bs[b][wbase8]);
  };

  stage(0, 0);
  __syncthreads();
  int buf = 0;
  for (int k0 = 0; k0 < K; k0 += 32) {
    if (k0 + 32 < K) stage(buf ^ 1, k0 + 32);
    bf16x8 af = *(const bf16x8*)&As[buf][(w * 16 + l15) * 32 + lhi * 8];
    bf16x8 bfr[4];
#pragma unroll
    for (int n = 0; n < 4; ++n)
      bfr[n] = *(const bf16x8*)&Bs[buf][(n * 16 + l15) * 32 + lhi * 8];
#pragma unroll
    for (int n = 0; n < 4; ++n)
      acc[n] = MFMA16(af, bfr[n], acc[n]);
    __syncthreads();
    buf ^= 1;
  }

  long row = tm + w * 16 + lhi * 4;
#pragma unroll
  for (int n = 0; n < 4; ++n) {
    long col = tn + n * 16 + l15;
    float bv = bias[col];
#pragma unroll
    for (int r = 0; r < 4; ++r)
      Cout[(row + r) * (long)N + col] = acc[n][r] + bv;
  }
}

// ---------- attention v9: b128 PV via permuted vT; V-reads hoisted before exp -------
// 3-ring counted-vmcnt staging (R12). Per tile: {K reads x8 b128} {V reads x8 b128}
// {QK MFMA + exp (VALU)} {denom + PV MFMA}. DS FIFO => V latency hides under QK/exp.
__global__ __launch_bounds__(256) void attn_fwd(const unsigned short* __restrict__ qkv,
                                                const unsigned short* __restrict__ vT,
                                                unsigned short* __restrict__ attnb) {
  __shared__ unsigned short Ks[3][4096];   // [key 64][d 64], 16B-chunk XOR-swizzled
  __shared__ unsigned short Vs[3][4096];   // [d 64][key 64 permuted], XOR-swizzled
  int tid = threadIdx.x;
  int lane = tid & 63, w = tid >> 6;
  int l15 = lane & 15, lhi = lane >> 4;
  int sw = l15 & 7;
  // T1: chunk so each XCD owns 6 consecutive heads (1.5 MB K/V fits its L2)
  int lin = blockIdx.x + gridDim.x * blockIdx.y;           // HW dispatch order
  int swz = xcd_swz(lin, 768);
  int qt = swz & 15, bh = swz >> 4;
  int b = bh / 12, h = bh % 12;

  // Q fragment FIRST (oldest in vmcnt ledger): B-operand for swapped QK^T
  int qrl = w * 16 + l15;                 // row % 64
  bf16x8 qf0 = {0, 0, 0, 0, 0, 0, 0, 0}, qf1 = {0, 0, 0, 0, 0, 0, 0, 0};
  if (qrl % 3 != 0) {
    const unsigned short* qp =
        &qkv[(size_t)(b * 1024 + qt * 64 + qrl) * 2304 + h * 64 + lhi * 8];
    qf0 = *(const bf16x8*)qp;
    qf1 = *(const bf16x8*)(qp + 32);
  }

  // staging geometry: LDS[row][c] = G[row][c ^ (row&7)], row = tid>>3, c = tid&7
  int r8 = lane >> 3;
  int cK = ((lane & 7) ^ r8) << 3;                  // pre-swizzled source chunk
  int wbase = (tid & ~63) * 8;                      // wave-uniform LDS elem base
  const unsigned short* kg = qkv + (size_t)(b * 1024) * 2304 + 768 + h * 64 + cK;
  const unsigned short* vg = vT + (size_t)bh * 65536 + cK;

  auto stage = [&](int bufi, int t) {
    size_t k0 = (size_t)t * 64;
#pragma unroll
    for (int p = 0; p < 2; ++p) {
      int row = p * 32 + w * 8 + r8;
      gload16(kg + (k0 + row) * 2304, &Ks[bufi][p * 2048 + wbase]);
      gload16(vg + (size_t)row * 1024 + k0, &Vs[bufi][p * 2048 + wbase]);
    }
  };

  stage(0, 0);
  stage(1, 1);

  const f32x4 z4 = {0.f, 0.f, 0.f, 0.f};
  f32x4 acc[4];
#pragma unroll
  for (int dg = 0; dg < 4; ++dg) acc[dg] = z4;
  f32x4 accd = z4;                        // denominator via MFMA(P, ones)
  const short one_bf = (short)0x3F80;     // bf16 1.0
  const bf16x8 ONES = {one_bf, one_bf, one_bf, one_bf, one_bf, one_bf, one_bf, one_bf};

  int bc = 0, bp = 2;                     // compute buf, prefetch buf (ring of 3)
  for (int t = 0; t < 16; ++t) {
    if (t < 15) VMCNT4(); else VMCNT0();  // own tile-t (and qf at t=0) landed
    __builtin_amdgcn_s_barrier();         // all waves' tile-t loads landed
    if (t + 2 < 16) stage(bp, t + 2);     // buf (bc-1): free after barrier
    const unsigned short* ks = Ks[bc];
    const unsigned short* vs = Vs[bc];

    // K fragments (8 x b128) — needed first, issued first
    bf16x8 kf[4][2];
#pragma unroll
    for (int g = 0; g < 4; ++g) {
      const unsigned short* kr = &ks[(g * 16 + l15) * 64];
      kf[g][0] = *(const bf16x8*)&kr[(lhi ^ sw) << 3];
      kf[g][1] = *(const bf16x8*)&kr[((lhi + 4) ^ sw) << 3];
    }
    // V fragments (8 x b128): permuted-key layout => one chunk per (dg,kh).
    // DS pipe is FIFO: these complete while QK MFMA + exp run.
    bf16x8 vfr[4][2];
#pragma unroll
    for (int dg = 0; dg < 4; ++dg) {
      const unsigned short* vr = &vs[(dg * 16 + l15) * 64];
#pragma unroll
      for (int kh = 0; kh < 2; ++kh)
        vfr[dg][kh] = *(const bf16x8*)&vr[((kh * 4 + lhi) ^ sw) << 3];
    }

    // swapped QK^T: lane holds P[qrow=l15][key g*16+lhi*4+r]
    bf16x8 paf[2];
#pragma unroll
    for (int g = 0; g < 4; ++g) {
      f32x4 sg = MFMA16(kf[g][0], qf0, z4);
      sg = MFMA16(kf[g][1], qf1, sg);
#pragma unroll
      for (int r = 0; r < 4; ++r) {
        // p = exp(s/8) = 2^(s*0.125*log2 e); clamps inert (|s|<~2, p in [e^-2,e^2])
        float pv = exp2f(sg[r] * 0.18033688011f);
        paf[g >> 1][(g & 1) * 4 + r] = (short)f2bf(pv);
      }
    }

    // denominator + PV (paf key order matches vfr chunk order)
    __builtin_amdgcn_s_setprio(1);
    accd = MFMA16(paf[0], ONES, accd);
    accd = MFMA16(paf[1], ONES, accd);
#pragma unroll
    for (int dg = 0; dg < 4; ++dg)
#pragma unroll
      for (int kh = 0; kh < 2; ++kh)
        acc[dg] = MFMA16(paf[kh], vfr[dg][kh], acc[dg]);
    __builtin_amdgcn_s_setprio(0);
    bc = (bc == 2) ? 0 : bc + 1;
    bp = (bp == 2) ? 0 : bp + 1;
  }

  // denominator for qrow=lhi*4+r sits in accd[r] (replicated over l15) — no shuffles
#pragma unroll
  for (int r = 0; r < 4; ++r) {
    float inv = 1.f / (accd[r] + 1e-10f);
    int orow = qt * 64 + w * 16 + lhi * 4 + r;
    size_t obase = (size_t)(b * 1024 + orow) * 768 + h * 64;
#pragma unroll
    for (int dg = 0; dg < 4; ++dg)
      attnb[obase + dg * 16 + l15] = f2bf(acc[dg][r] * inv);
  }
}

extern "C" void kernel_launch(void* const* d_in, const int* in_sizes, int n_in,
                              void* d_out, int out_size, void* d_ws, size_t ws_size,
                              hipStream_t stream) {
  (void)in_sizes; (void)n_in; (void)out_size; (void)ws_size;
  const float* x    = (const float*)d_in[0];
  const int*   idx  = (const int*)d_in[1];
  const float* se   = (const float*)d_in[2];
  const float* wqkv = (const float*)d_in[3];
  const float* wout = (const float*)d_in[4];
  const float* bout = (const float*)d_in[5];
  float* out = (float*)d_out;

  char* ws = (char*)d_ws;
  unsigned short* xb    = (unsigned short*)(ws);             //  6,291,456 B
  unsigned short* wqkvb = (unsigned short*)(ws + 6291456);   //  3,538,944 B
  unsigned short* woutb = (unsigned short*)(ws + 9830400);   //  1,179,648 B
  unsigned short* qkvb  = (unsigned short*)(ws + 11010048);  // 18,874,368 B (Q/K used)
  unsigned short* vT    = (unsigned short*)(ws + 29884416);  //  6,291,456 B
  unsigned short* attnb = (unsigned short*)(ws + 36175872);  //  6,291,456 B

  prep_all<<<5376, 256, 0, stream>>>(x, idx, se, wqkv, wout, xb, wqkvb, woutb);
  gemm_qkv<<<dim3(32, 18), 256, 0, stream>>>(xb, wqkvb, qkvb, vT, 2304, 768);
  attn_fwd<<<dim3(16, 48), 256, 0, stream>>>(qkvb, vT, attnb);
  gemm_out<<<dim3(64, 12), 256, 0, stream>>>(attnb, woutb, out, bout, 768, 768);
}